// Round 1
// baseline (199.602 us; speedup 1.0000x reference)
//
#include <hip/hip_runtime.h>
#include <math.h>

#define BB 8
#define CC 32
#define NTOK 241   // 4(q 2x2) + 121 + 64 + 36 + 16
#define NKV 237
#define YC 31      // 2 + 11 + 8 + 6 + 4 pooled widths along W

// ---------------------------------------------------------------------------
// Kernel A: separable adaptive pooling. One block per (b,c) plane (512x512).
// Phase 1: per-row prefix sum -> Y[row][31] (all pooled widths along W) in LDS.
// Phase 2: pool Y over row-windows -> 241 pooled values -> global ws.
// ---------------------------------------------------------------------------
__global__ __launch_bounds__(512) void pool_kernel(const float* __restrict__ x,
                                                   float* __restrict__ pooled) {
  __shared__ float Ybuf[512 * YC];   // 63,488 B
  __shared__ float Prow[8][512];     // 16,384 B (per-wave prefix row)

  const int plane = blockIdx.x;              // b*32 + c
  const float* xp = x + (size_t)plane * (512 * 512);
  const int tid = threadIdx.x, wave = tid >> 6, lane = tid & 63;

  // per-lane W-window (lane < 31): adaptive pool boundaries
  int cs = 0, ce = 1; float cinv = 0.f;
  if (lane < YC) {
    int p, jj;
    if (lane < 2)       { p = 2;  jj = lane; }
    else if (lane < 13) { p = 11; jj = lane - 2; }
    else if (lane < 21) { p = 8;  jj = lane - 13; }
    else if (lane < 27) { p = 6;  jj = lane - 21; }
    else                { p = 4;  jj = lane - 27; }
    cs = (jj * 512) / p;
    ce = ((jj + 1) * 512 + p - 1) / p;
    cinv = 1.0f / (float)(ce - cs);
  }

  float* prw = Prow[wave];

  // prefetch first row (each wave owns rows wave, wave+8, ...)
  float4 a  = *(const float4*)(xp + wave * 512 + 4 * lane);
  float4 bq = *(const float4*)(xp + wave * 512 + 256 + 4 * lane);

  for (int r = wave; r < 512; r += 8) {
    float4 an = make_float4(0.f, 0.f, 0.f, 0.f), bn = an;
    if (r + 8 < 512) {
      an = *(const float4*)(xp + (r + 8) * 512 + 4 * lane);
      bn = *(const float4*)(xp + (r + 8) * 512 + 256 + 4 * lane);
    }
    // in-lane inclusive prefix (two half-rows: cols 4l.., cols 256+4l..)
    float pa0 = a.x, pa1 = pa0 + a.y, pa2 = pa1 + a.z, pa3 = pa2 + a.w;
    float pb0 = bq.x, pb1 = pb0 + bq.y, pb2 = pb1 + bq.z, pb3 = pb2 + bq.w;
    float sA = pa3, sB = pb3;
#pragma unroll
    for (int d = 1; d < 64; d <<= 1) {
      float tA = __shfl_up(sA, d);
      float tB = __shfl_up(sB, d);
      if (lane >= d) { sA += tA; sB += tB; }
    }
    float exA = sA - pa3;
    float totA = __shfl(sA, 63);
    float exB = sB - pb3 + totA;
    float4 PA = make_float4(exA + pa0, exA + pa1, exA + pa2, exA + pa3);
    float4 PB = make_float4(exB + pb0, exB + pb1, exB + pb2, exB + pb3);
    *(float4*)(prw + 4 * lane) = PA;
    *(float4*)(prw + 256 + 4 * lane) = PB;
    asm volatile("s_waitcnt lgkmcnt(0)" ::: "memory");  // wave-local LDS RAW
    if (lane < YC) {
      float sum = prw[ce - 1] - (cs ? prw[cs - 1] : 0.0f);
      Ybuf[r * YC + lane] = sum * cinv;
    }
    a = an; bq = bn;
  }
  __syncthreads();

  // Phase 2: pool over rows
  if (tid < NTOK) {
    int k = tid, p, colb, kb;
    if (k < 4)        { p = 2;  colb = 0;  kb = 0; }
    else if (k < 125) { p = 11; colb = 2;  kb = 4; }
    else if (k < 189) { p = 8;  colb = 13; kb = 125; }
    else if (k < 225) { p = 6;  colb = 21; kb = 189; }
    else              { p = 4;  colb = 27; kb = 225; }
    int idx = k - kb;
    int i = idx / p, j = idx - i * p;
    int s = (i * 512) / p, e = ((i + 1) * 512 + p - 1) / p;
    float s0 = 0.f, s1 = 0.f, s2 = 0.f, s3 = 0.f;
    int r = s;
    for (; r + 4 <= e; r += 4) {
      s0 += Ybuf[(r + 0) * YC + colb + j];
      s1 += Ybuf[(r + 1) * YC + colb + j];
      s2 += Ybuf[(r + 2) * YC + colb + j];
      s3 += Ybuf[(r + 3) * YC + colb + j];
    }
    for (; r < e; ++r) s0 += Ybuf[r * YC + colb + j];
    float sum = (s0 + s1) + (s2 + s3);
    pooled[(size_t)plane * NTOK + k] = sum / (float)(e - s);
  }
}

// ---------------------------------------------------------------------------
// Kernel B: token pipeline (dw-conv residual, LN, q/kv linears, attention,
// proj). One block per batch element.
// ---------------------------------------------------------------------------
__global__ __launch_bounds__(512) void attn_kernel(
    const float* __restrict__ pooled,
    const float* __restrict__ q_w, const float* __restrict__ q_b,
    const float* __restrict__ kv_w, const float* __restrict__ kv_b,
    const float* __restrict__ proj_w, const float* __restrict__ proj_b,
    const float* __restrict__ norm_g, const float* __restrict__ norm_b,
    const float* __restrict__ dconv_w, const float* __restrict__ dconv_b,
    float* __restrict__ o_out) {
  __shared__ float pl[CC * NTOK];      // 30,848 B  [c][241]
  __shared__ float toks[NKV][33];      // 31,284 B  (padded vs 32-bank)
  __shared__ float kvls[NKV][65];      // 61,620 B  (k: 0..31, v: 32..63)
  __shared__ float kvw[CC * 64];       //  8,192 B
  __shared__ float dw[4 * CC * 9];     //  4,608 B
  __shared__ float dbias[4 * CC];
  __shared__ float qbias[CC], kvb[64], gln[CC], bln[CC];
  __shared__ float qtok[4][CC];
  __shared__ float attno[4][33];

  const int b = blockIdx.x, tid = threadIdx.x;
  const float* plg = pooled + (size_t)b * CC * NTOK;
  for (int i = tid; i < CC * NTOK; i += 512) pl[i] = plg[i];
  for (int i = tid; i < CC * 64; i += 512) kvw[i] = kv_w[i];
  for (int i = tid; i < 4 * CC * 9; i += 512) dw[i] = dconv_w[i];
  if (tid < 4 * CC) dbias[tid] = dconv_b[tid];
  if (tid < CC) { qbias[tid] = q_b[tid]; gln[tid] = norm_g[tid]; bln[tid] = norm_b[tid]; }
  if (tid >= 64 && tid < 128) kvb[tid - 64] = kv_b[tid - 64];
  __syncthreads();

  // depthwise 3x3 conv (SAME, zero pad) + residual -> toks
  for (int item = tid; item < NKV * CC; item += 512) {
    int t = item >> 5, c = item & 31;
    int l, p, kb_, tb;
    if (t < 121)      { l = 0; p = 11; kb_ = 4;   tb = 0; }
    else if (t < 185) { l = 1; p = 8;  kb_ = 125; tb = 121; }
    else if (t < 221) { l = 2; p = 6;  kb_ = 189; tb = 185; }
    else              { l = 3; p = 4;  kb_ = 225; tb = 221; }
    int ti = t - tb;
    int i = ti / p, j = ti - i * p;
    const float* plc = pl + c * NTOK + kb_;
    const float* w9 = dw + (l * CC + c) * 9;
    float acc = dbias[l * CC + c];
#pragma unroll
    for (int dy = -1; dy <= 1; ++dy)
#pragma unroll
      for (int dx = -1; dx <= 1; ++dx) {
        int ii = i + dy, jj = j + dx;
        if (ii >= 0 && ii < p && jj >= 0 && jj < p)
          acc += w9[(dy + 1) * 3 + (dx + 1)] * plc[ii * p + jj];
      }
    toks[t][c] = plc[i * p + j] + acc;
  }
  __syncthreads();

  // LayerNorm over C (threads 0..236) ; q linear (threads 384..511) in parallel
  if (tid < NKV) {
    float xv[32]; float m = 0.f;
#pragma unroll
    for (int c = 0; c < 32; ++c) { xv[c] = toks[tid][c]; m += xv[c]; }
    m *= (1.0f / 32.0f);
    float v = 0.f;
#pragma unroll
    for (int c = 0; c < 32; ++c) { float d = xv[c] - m; v += d * d; }
    v *= (1.0f / 32.0f);
    float rs = rsqrtf(v + 1e-5f);
#pragma unroll
    for (int c = 0; c < 32; ++c) toks[tid][c] = (xv[c] - m) * rs * gln[c] + bln[c];
  } else if (tid >= 384) {
    int it = tid - 384;               // 128 items: (n,u)
    int n = it >> 5, u = it & 31;
    float acc = qbias[u];
#pragma unroll
    for (int c = 0; c < 32; ++c) acc += pl[c * NTOK + n] * q_w[c * 32 + u];
    qtok[n][u] = acc * 0.25f;         // fold scale = hd^-0.5
  }
  __syncthreads();

  // kv = toks_ln @ kv_w + kv_b   (237 x 64)
  for (int item = tid; item < NKV * 64; item += 512) {
    int t = item >> 6, u = item & 63;
    float acc = kvb[u];
#pragma unroll
    for (int c = 0; c < 32; ++c) acc += toks[t][c] * kvw[c * 64 + u];
    kvls[t][u] = acc;
  }
  __syncthreads();

  // attention: 8 waves <-> 8 (head, query) pairs
  {
    int wave = tid >> 6, lane = tid & 63;
    int h = wave >> 2, qi = wave & 3;
    float qv[16];
#pragma unroll
    for (int d = 0; d < 16; ++d) qv[d] = qtok[qi][h * 16 + d];
    float sc[4];
#pragma unroll
    for (int m = 0; m < 4; ++m) {
      int t = lane + m * 64;
      float s = -1e30f;
      if (t < NKV) {
        s = 0.f;
#pragma unroll
        for (int d = 0; d < 16; ++d) s += qv[d] * kvls[t][h * 16 + d];
      }
      sc[m] = s;
    }
    float mx = fmaxf(fmaxf(sc[0], sc[1]), fmaxf(sc[2], sc[3]));
#pragma unroll
    for (int d = 1; d < 64; d <<= 1) mx = fmaxf(mx, __shfl_xor(mx, d));
    float pr[4]; float ssum = 0.f;
#pragma unroll
    for (int m = 0; m < 4; ++m) {
      int t = lane + m * 64;
      pr[m] = (t < NKV) ? expf(sc[m] - mx) : 0.0f;
      ssum += pr[m];
    }
#pragma unroll
    for (int d = 1; d < 64; d <<= 1) ssum += __shfl_xor(ssum, d);
    float acc[16];
#pragma unroll
    for (int d = 0; d < 16; ++d) acc[d] = 0.f;
#pragma unroll
    for (int m = 0; m < 4; ++m) {
      int t = lane + m * 64;
      if (t < NKV) {
        float p = pr[m];
#pragma unroll
        for (int d = 0; d < 16; ++d) acc[d] += p * kvls[t][32 + h * 16 + d];
      }
    }
#pragma unroll
    for (int d = 0; d < 16; ++d) {
#pragma unroll
      for (int s = 1; s < 64; s <<= 1) acc[d] += __shfl_xor(acc[d], s);
    }
    if (lane == 0) {
      float inv = 1.0f / ssum;
#pragma unroll
      for (int d = 0; d < 16; ++d) attno[qi][h * 16 + d] = acc[d] * inv;
    }
  }
  __syncthreads();

  // proj: (4 x 32) @ proj_w + proj_b -> o_out[(b*32+u)*4 + n]
  if (tid < 128) {
    int n = tid >> 5, u = tid & 31;
    float acc = proj_b[u];
#pragma unroll
    for (int c = 0; c < 32; ++c) acc += attno[n][c] * proj_w[c * 32 + u];
    o_out[((size_t)b * 32 + u) * 4 + n] = acc;
  }
}

// ---------------------------------------------------------------------------
// Kernel C: bilinear upsample 2x2 -> 512x512 (align_corners=False, clamped).
// grid = 256 planes * 8 row-chunks, 256 threads, float4 stores.
// ---------------------------------------------------------------------------
__global__ __launch_bounds__(256) void upsample_kernel(const float* __restrict__ o_in,
                                                       float* __restrict__ out) {
  const int plane = blockIdx.x >> 3;
  const int chunk = blockIdx.x & 7;
  const int tid = threadIdx.x;
  const int sub = tid >> 7, col4 = tid & 127;

  const float o00 = o_in[plane * 4 + 0];
  const float o01 = o_in[plane * 4 + 1];
  const float o10 = o_in[plane * 4 + 2];
  const float o11 = o_in[plane * 4 + 3];

  float top[4], bot[4];
#pragma unroll
  for (int k = 0; k < 4; ++k) {
    float c = (float)(4 * col4 + k) + 0.5f;
    float ww = c * (1.0f / 256.0f) - 0.5f;
    ww = fminf(fmaxf(ww, 0.0f), 1.0f);
    top[k] = o00 + ww * (o01 - o00);
    bot[k] = o10 + ww * (o11 - o10);
  }
  float* outp = out + (size_t)plane * (512 * 512);
  const int r0 = chunk * 64;
  for (int i = 0; i < 32; ++i) {
    int r = r0 + 2 * i + sub;
    float wh = ((float)r + 0.5f) * (1.0f / 256.0f) - 0.5f;
    wh = fminf(fmaxf(wh, 0.0f), 1.0f);
    float4 v;
    v.x = top[0] + wh * (bot[0] - top[0]);
    v.y = top[1] + wh * (bot[1] - top[1]);
    v.z = top[2] + wh * (bot[2] - top[2]);
    v.w = top[3] + wh * (bot[3] - top[3]);
    *(float4*)(outp + r * 512 + 4 * col4) = v;
  }
}

extern "C" void kernel_launch(void* const* d_in, const int* in_sizes, int n_in,
                              void* d_out, int out_size, void* d_ws, size_t ws_size,
                              hipStream_t stream) {
  const float* x       = (const float*)d_in[0];
  const float* q_w     = (const float*)d_in[1];
  const float* q_b     = (const float*)d_in[2];
  const float* kv_w    = (const float*)d_in[3];
  const float* kv_b    = (const float*)d_in[4];
  const float* proj_w  = (const float*)d_in[5];
  const float* proj_b  = (const float*)d_in[6];
  const float* norm_g  = (const float*)d_in[7];
  const float* norm_b  = (const float*)d_in[8];
  const float* dconv_w = (const float*)d_in[9];
  const float* dconv_b = (const float*)d_in[10];
  float* out = (float*)d_out;

  float* pooled = (float*)d_ws;                 // 256*241 floats
  float* o_ws   = pooled + (size_t)BB * CC * NTOK;  // 1024 floats

  pool_kernel<<<BB * CC, 512, 0, stream>>>(x, pooled);
  attn_kernel<<<BB, 512, 0, stream>>>(pooled, q_w, q_b, kv_w, kv_b, proj_w,
                                      proj_b, norm_g, norm_b, dconv_w, dconv_b,
                                      o_ws);
  upsample_kernel<<<BB * CC * 8, 256, 0, stream>>>(o_ws, out);
}

// Round 2
// 196.399 us; speedup vs baseline: 1.0163x; 1.0163x over previous
//
#include <hip/hip_runtime.h>
#include <math.h>

#define BB 8
#define CC 32
#define NTOK 241   // 4(q 2x2) + 121 + 64 + 36 + 16
#define NKV 237
#define YROWS 31   // 2 + 11 + 8 + 6 + 4 pooled heights
#define YPAD 520

// ---------------------------------------------------------------------------
// Kernel A (v2): H-first separable adaptive pooling. One block per (b,c)
// plane. Thread = one column; walks 512 rows with 5 per-level window
// accumulators (no cross-lane ops). Triple-buffered 16-row chunks keep 32
// loads/lane in flight. Phase 2 pools the 31x512 LDS intermediate along W.
// ---------------------------------------------------------------------------
struct LvlState { int i, s, e; float acc; };

template <int P, int KB>
__device__ __forceinline__ void step_lvl(LvlState& st, float v, int r,
                                         float (*Y)[YPAD], int c) {
  st.acc += v;
  if (r == st.e - 1) {                       // wave-uniform branch
    Y[KB + st.i][c] = st.acc * (1.0f / (float)(st.e - st.s));
    st.i++;
    int sn = (st.i * 512) / P;               // adaptive windows overlap <=1 row
    st.e = ((st.i + 1) * 512 + P - 1) / P;
    st.acc = (sn <= r) ? v : 0.0f;
    st.s = sn;
  }
}

__device__ __forceinline__ void load16(float (&buf)[16],
                                       const float* __restrict__ xp, int r0) {
#pragma unroll
  for (int u = 0; u < 16; ++u) buf[u] = xp[(size_t)(r0 + u) * 512];
}

__device__ __forceinline__ void proc16(float (&buf)[16], int r0, LvlState& sq,
                                       LvlState& s11, LvlState& s8,
                                       LvlState& s6, LvlState& s4,
                                       float (*Y)[YPAD], int c) {
#pragma unroll
  for (int u = 0; u < 16; ++u) {
    float v = buf[u];
    int r = r0 + u;
    step_lvl<2, 0>(sq, v, r, Y, c);
    step_lvl<11, 2>(s11, v, r, Y, c);
    step_lvl<8, 13>(s8, v, r, Y, c);
    step_lvl<6, 21>(s6, v, r, Y, c);
    step_lvl<4, 27>(s4, v, r, Y, c);
  }
}

__global__ __launch_bounds__(512) void pool_kernel(const float* __restrict__ x,
                                                   float* __restrict__ pooled) {
  __shared__ float Ybuf[YROWS][YPAD];  // 64,480 B

  const int plane = blockIdx.x;        // b*32 + c
  const int c = threadIdx.x;           // column 0..511
  const float* xp = x + (size_t)plane * (512 * 512) + c;

  LvlState sq{0, 0, 256, 0.f};
  LvlState s11{0, 0, 47, 0.f};
  LvlState s8{0, 0, 64, 0.f};
  LvlState s6{0, 0, 86, 0.f};
  LvlState s4{0, 0, 128, 0.f};

  float A[16], B[16], Cb[16];
  load16(A, xp, 0);
  load16(B, xp, 16);
  for (int rb = 0; rb < 480; rb += 48) {
    load16(Cb, xp, rb + 32);
    proc16(A, rb, sq, s11, s8, s6, s4, Ybuf, c);
    load16(A, xp, rb + 48);
    proc16(B, rb + 16, sq, s11, s8, s6, s4, Ybuf, c);
    load16(B, xp, rb + 64);
    proc16(Cb, rb + 32, sq, s11, s8, s6, s4, Ybuf, c);
  }
  proc16(A, 480, sq, s11, s8, s6, s4, Ybuf, c);
  proc16(B, 496, sq, s11, s8, s6, s4, Ybuf, c);
  __syncthreads();

  // Phase 2: pool along W from LDS
  if (c < NTOK) {
    int k = c, p, kbase, kb;
    if (k < 4)        { p = 2;  kbase = 0;  kb = 0; }
    else if (k < 125) { p = 11; kbase = 2;  kb = 4; }
    else if (k < 189) { p = 8;  kbase = 13; kb = 125; }
    else if (k < 225) { p = 6;  kbase = 21; kb = 189; }
    else              { p = 4;  kbase = 27; kb = 225; }
    int idx = k - kb, i = idx / p, j = idx - i * p;
    int s = (j * 512) / p, e = ((j + 1) * 512 + p - 1) / p;
    const float* row = &Ybuf[kbase + i][0];
    float t0 = 0.f, t1 = 0.f, t2 = 0.f, t3 = 0.f;
    int cc = s;
    for (; cc + 4 <= e; cc += 4) {
      t0 += row[cc]; t1 += row[cc + 1]; t2 += row[cc + 2]; t3 += row[cc + 3];
    }
    for (; cc < e; ++cc) t0 += row[cc];
    pooled[(size_t)plane * NTOK + k] = ((t0 + t1) + (t2 + t3)) / (float)(e - s);
  }
}

// ---------------------------------------------------------------------------
// Kernel B: token pipeline (dw-conv residual, LN, q/kv linears, attention,
// proj). One block per batch element.
// ---------------------------------------------------------------------------
__global__ __launch_bounds__(512) void attn_kernel(
    const float* __restrict__ pooled,
    const float* __restrict__ q_w, const float* __restrict__ q_b,
    const float* __restrict__ kv_w, const float* __restrict__ kv_b,
    const float* __restrict__ proj_w, const float* __restrict__ proj_b,
    const float* __restrict__ norm_g, const float* __restrict__ norm_b,
    const float* __restrict__ dconv_w, const float* __restrict__ dconv_b,
    float* __restrict__ o_out) {
  __shared__ float pl[CC * NTOK];      // 30,848 B  [c][241]
  __shared__ float toks[NKV][33];
  __shared__ float kvls[NKV][65];      // k: 0..31, v: 32..63
  __shared__ float kvw[CC * 64];
  __shared__ float dw[4 * CC * 9];
  __shared__ float dbias[4 * CC];
  __shared__ float qbias[CC], kvb[64], gln[CC], bln[CC];
  __shared__ float qtok[4][CC];
  __shared__ float attno[4][33];

  const int b = blockIdx.x, tid = threadIdx.x;
  const float* plg = pooled + (size_t)b * CC * NTOK;
  for (int i = tid; i < CC * NTOK; i += 512) pl[i] = plg[i];
  for (int i = tid; i < CC * 64; i += 512) kvw[i] = kv_w[i];
  for (int i = tid; i < 4 * CC * 9; i += 512) dw[i] = dconv_w[i];
  if (tid < 4 * CC) dbias[tid] = dconv_b[tid];
  if (tid < CC) { qbias[tid] = q_b[tid]; gln[tid] = norm_g[tid]; bln[tid] = norm_b[tid]; }
  if (tid >= 64 && tid < 128) kvb[tid - 64] = kv_b[tid - 64];
  __syncthreads();

  // depthwise 3x3 conv (SAME, zero pad) + residual -> toks
  for (int item = tid; item < NKV * CC; item += 512) {
    int t = item >> 5, c = item & 31;
    int l, p, kb_, tb;
    if (t < 121)      { l = 0; p = 11; kb_ = 4;   tb = 0; }
    else if (t < 185) { l = 1; p = 8;  kb_ = 125; tb = 121; }
    else if (t < 221) { l = 2; p = 6;  kb_ = 189; tb = 185; }
    else              { l = 3; p = 4;  kb_ = 225; tb = 221; }
    int ti = t - tb;
    int i = ti / p, j = ti - i * p;
    const float* plc = pl + c * NTOK + kb_;
    const float* w9 = dw + (l * CC + c) * 9;
    float acc = dbias[l * CC + c];
#pragma unroll
    for (int dy = -1; dy <= 1; ++dy)
#pragma unroll
      for (int dx = -1; dx <= 1; ++dx) {
        int ii = i + dy, jj = j + dx;
        if (ii >= 0 && ii < p && jj >= 0 && jj < p)
          acc += w9[(dy + 1) * 3 + (dx + 1)] * plc[ii * p + jj];
      }
    toks[t][c] = plc[i * p + j] + acc;
  }
  __syncthreads();

  // LayerNorm over C (threads 0..236) ; q linear (threads 384..511)
  if (tid < NKV) {
    float xv[32]; float m = 0.f;
#pragma unroll
    for (int c = 0; c < 32; ++c) { xv[c] = toks[tid][c]; m += xv[c]; }
    m *= (1.0f / 32.0f);
    float v = 0.f;
#pragma unroll
    for (int c = 0; c < 32; ++c) { float d = xv[c] - m; v += d * d; }
    v *= (1.0f / 32.0f);
    float rs = rsqrtf(v + 1e-5f);
#pragma unroll
    for (int c = 0; c < 32; ++c) toks[tid][c] = (xv[c] - m) * rs * gln[c] + bln[c];
  } else if (tid >= 384) {
    int it = tid - 384;               // 128 items: (n,u)
    int n = it >> 5, u = it & 31;
    float acc = qbias[u];
#pragma unroll
    for (int c = 0; c < 32; ++c) acc += pl[c * NTOK + n] * q_w[c * 32 + u];
    qtok[n][u] = acc * 0.25f;         // fold scale = hd^-0.5
  }
  __syncthreads();

  // kv = toks_ln @ kv_w + kv_b   (237 x 64)
  for (int item = tid; item < NKV * 64; item += 512) {
    int t = item >> 6, u = item & 63;
    float acc = kvb[u];
#pragma unroll
    for (int c = 0; c < 32; ++c) acc += toks[t][c] * kvw[c * 64 + u];
    kvls[t][u] = acc;
  }
  __syncthreads();

  // attention: 8 waves <-> 8 (head, query) pairs
  {
    int wave = tid >> 6, lane = tid & 63;
    int h = wave >> 2, qi = wave & 3;
    float qv[16];
#pragma unroll
    for (int d = 0; d < 16; ++d) qv[d] = qtok[qi][h * 16 + d];
    float sc[4];
#pragma unroll
    for (int m = 0; m < 4; ++m) {
      int t = lane + m * 64;
      float s = -1e30f;
      if (t < NKV) {
        s = 0.f;
#pragma unroll
        for (int d = 0; d < 16; ++d) s += qv[d] * kvls[t][h * 16 + d];
      }
      sc[m] = s;
    }
    float mx = fmaxf(fmaxf(sc[0], sc[1]), fmaxf(sc[2], sc[3]));
#pragma unroll
    for (int d = 1; d < 64; d <<= 1) mx = fmaxf(mx, __shfl_xor(mx, d));
    float pr[4]; float ssum = 0.f;
#pragma unroll
    for (int m = 0; m < 4; ++m) {
      int t = lane + m * 64;
      pr[m] = (t < NKV) ? expf(sc[m] - mx) : 0.0f;
      ssum += pr[m];
    }
#pragma unroll
    for (int d = 1; d < 64; d <<= 1) ssum += __shfl_xor(ssum, d);
    float acc[16];
#pragma unroll
    for (int d = 0; d < 16; ++d) acc[d] = 0.f;
#pragma unroll
    for (int m = 0; m < 4; ++m) {
      int t = lane + m * 64;
      if (t < NKV) {
        float p = pr[m];
#pragma unroll
        for (int d = 0; d < 16; ++d) acc[d] += p * kvls[t][32 + h * 16 + d];
      }
    }
#pragma unroll
    for (int d = 0; d < 16; ++d) {
#pragma unroll
      for (int s = 1; s < 64; s <<= 1) acc[d] += __shfl_xor(acc[d], s);
    }
    if (lane == 0) {
      float inv = 1.0f / ssum;
#pragma unroll
      for (int d = 0; d < 16; ++d) attno[qi][h * 16 + d] = acc[d] * inv;
    }
  }
  __syncthreads();

  // proj: (4 x 32) @ proj_w + proj_b -> o_out[(b*32+u)*4 + n]
  if (tid < 128) {
    int n = tid >> 5, u = tid & 31;
    float acc = proj_b[u];
#pragma unroll
    for (int c = 0; c < 32; ++c) acc += attno[n][c] * proj_w[c * 32 + u];
    o_out[((size_t)b * 32 + u) * 4 + n] = acc;
  }
}

// ---------------------------------------------------------------------------
// Kernel C: bilinear upsample 2x2 -> 512x512 (align_corners=False, clamped).
// grid = 256 planes * 8 row-chunks, 256 threads, float4 stores.
// ---------------------------------------------------------------------------
__global__ __launch_bounds__(256) void upsample_kernel(const float* __restrict__ o_in,
                                                       float* __restrict__ out) {
  const int plane = blockIdx.x >> 3;
  const int chunk = blockIdx.x & 7;
  const int tid = threadIdx.x;
  const int sub = tid >> 7, col4 = tid & 127;

  const float o00 = o_in[plane * 4 + 0];
  const float o01 = o_in[plane * 4 + 1];
  const float o10 = o_in[plane * 4 + 2];
  const float o11 = o_in[plane * 4 + 3];

  float top[4], bot[4];
#pragma unroll
  for (int k = 0; k < 4; ++k) {
    float c = (float)(4 * col4 + k) + 0.5f;
    float ww = c * (1.0f / 256.0f) - 0.5f;
    ww = fminf(fmaxf(ww, 0.0f), 1.0f);
    top[k] = o00 + ww * (o01 - o00);
    bot[k] = o10 + ww * (o11 - o10);
  }
  float* outp = out + (size_t)plane * (512 * 512);
  const int r0 = chunk * 64;
  for (int i = 0; i < 32; ++i) {
    int r = r0 + 2 * i + sub;
    float wh = ((float)r + 0.5f) * (1.0f / 256.0f) - 0.5f;
    wh = fminf(fmaxf(wh, 0.0f), 1.0f);
    float4 v;
    v.x = top[0] + wh * (bot[0] - top[0]);
    v.y = top[1] + wh * (bot[1] - top[1]);
    v.z = top[2] + wh * (bot[2] - top[2]);
    v.w = top[3] + wh * (bot[3] - top[3]);
    *(float4*)(outp + r * 512 + 4 * col4) = v;
  }
}

extern "C" void kernel_launch(void* const* d_in, const int* in_sizes, int n_in,
                              void* d_out, int out_size, void* d_ws, size_t ws_size,
                              hipStream_t stream) {
  const float* x       = (const float*)d_in[0];
  const float* q_w     = (const float*)d_in[1];
  const float* q_b     = (const float*)d_in[2];
  const float* kv_w    = (const float*)d_in[3];
  const float* kv_b    = (const float*)d_in[4];
  const float* proj_w  = (const float*)d_in[5];
  const float* proj_b  = (const float*)d_in[6];
  const float* norm_g  = (const float*)d_in[7];
  const float* norm_b  = (const float*)d_in[8];
  const float* dconv_w = (const float*)d_in[9];
  const float* dconv_b = (const float*)d_in[10];
  float* out = (float*)d_out;

  float* pooled = (float*)d_ws;                     // 256*241 floats
  float* o_ws   = pooled + (size_t)BB * CC * NTOK;  // 1024 floats

  pool_kernel<<<BB * CC, 512, 0, stream>>>(x, pooled);
  attn_kernel<<<BB, 512, 0, stream>>>(pooled, q_w, q_b, kv_w, kv_b, proj_w,
                                      proj_b, norm_g, norm_b, dconv_w, dconv_b,
                                      o_ws);
  upsample_kernel<<<BB * CC * 8, 256, 0, stream>>>(o_ws, out);
}